// Round 5
// baseline (615.733 us; speedup 1.0000x reference)
//
#include <hip/hip_runtime.h>

// fTN_NNiso: batched PEPS amplitude, MI355X.
// G=4 samples/block, 512 threads. Contraction phases: ONE WAVE PER SAMPLE
// (wave-internal LDS deps, no intra-site barriers). Bond matvec split:
// P-half serial (pre-barrier), Q-half on waves 4-7 concurrent with phases.
// All phase LDS access is b128 with XOR swizzles (row-parallel column writes).
// __launch_bounds__(512) — NOT (512,2): LDS (145KB) already limits to 1
// block/CU; the ",2" capped VGPRs at 128 and spilled the 128-float/thread
// accumulator set to scratch (round-4: WRITE_SIZE 73MB, 615us regression).
// peps strides (6,6,4,4,4,4,2): r:3072 c:512 l:128 rb:32 a:8 b:2 p:1

constexpr int   kNSites = 36;
constexpr int   kProj   = 51200;
constexpr float kEta    = 0.001f;
constexpr int   G       = 4;

// ---- LDS layout (float offsets) ----
constexpr int OFF_HT  = 0;                 // hT[k*4+g]                          256
constexpr int OFF_MS  = 256;               // MsT[g][r-1][d][ul ^ ((d&7)<<2)]    4*4096
constexpr int OFF_MS0 = OFF_MS + 16384;    // Ms0T[g][d*4+l]                     4*64
constexpr int OFF_MS5 = OFF_MS0 + 256;     // Ms5[g][u*4+l]                      4*64
constexpr int OFF_Q   = OFF_MS5 + 256;     // Q[buf][g][cq*68+ua]                2*4*1088
constexpr int OFF_M2  = OFF_Q + 8704;      // M2h[g][ua*32+(colh^((ua>>2&7)<<2))] (P aliased in [0:1024)) 4*2048
constexpr int OFF_A2  = OFF_M2 + 8192;     // A2[ab][g][lb*16 + a*4 + rb]        2*4*256
constexpr int OFF_VB  = OFF_A2 + 2048;     // vbuf[g][16]                        64
constexpr int LTOT    = OFF_VB + 64;       // 36160 floats = 144640 B

__device__ __forceinline__ float4 f4fma(float s, float4 a, float4 c) {
    c.x = fmaf(s, a.x, c.x); c.y = fmaf(s, a.y, c.y);
    c.z = fmaf(s, a.z, c.z); c.w = fmaf(s, a.w, c.w);
    return c;
}

// stage site tensor A[(l,b)][(a,rb)] for all G samples (masked pads)
__device__ __forceinline__ void stage_a2(float* L, const int* xl,
                                         const float* __restrict__ peps,
                                         int dst, int c, int r, int t0, int tstep)
{
    const int adim = (r == 0) ? 1 : 4;
    const int bdim = (r == 5) ? 1 : 4;
    const int rdim = (c == 5) ? 1 : 4;
    for (int idx = t0; idx < G * 256; idx += tstep) {
        int g = idx >> 8, rest = idx & 255;
        int lb = rest >> 4, arb = rest & 15;
        int l = lb >> 2, b = lb & 3, a = arb >> 2, rb = arb & 3;
        float v = 0.0f;
        if (a < adim && b < bdim && rb < rdim) {
            int p = xl[g * kNSites + r * 6 + c];
            v = peps[r * 3072 + c * 512 + l * 128 + rb * 32 + a * 8 + b * 2 + p];
        }
        L[dst + idx] = v;
    }
}

__global__ __launch_bounds__(512)
void tn_amp(const int* __restrict__ x,
            const float* __restrict__ peps,
            const float* __restrict__ base_proj,
            const float* __restrict__ W1,
            const float* __restrict__ b1,
            const float* __restrict__ W2,
            const float* __restrict__ b2,
            float* __restrict__ out,
            int batch)
{
    __shared__ __align__(16) float L[LTOT];
    __shared__ int xl[G * kNSites];

    const int tid   = threadIdx.x;
    const int wid   = tid >> 6;
    const int lane  = tid & 63;
    const int sBase = blockIdx.x * G;

    // ---- stage x ----
    if (tid < G * kNSites) {
        int g = tid / kNSites, ii = tid - g * kNSites;
        int s = sBase + g; if (s >= batch) s = batch - 1;
        xl[tid] = x[s * kNSites + ii];
    }
    __syncthreads();

    // ---- h (packed hT[k][g]) + zero Ms ----
    if (tid < 256) {
        int g = tid >> 6, k = tid & 63;
        float a = b1[k];
        for (int i = 0; i < kNSites; ++i)
            a = fmaf((float)xl[g * kNSites + i], W1[i * 64 + k], a);
        L[OFF_HT + k * 4 + g] = fmaxf(a, 0.0f);
    }
    for (int i = tid; i < 16896; i += 512) L[OFF_MS + i] = 0.0f; // MsT+Ms0+Ms5
    __syncthreads();

    // ---- init boundary MPS from column 0 ----
    for (int idx = tid; idx < 2048; idx += 512) {
        int g = idx >> 9, rem = idx & 511;
        int rr = rem >> 6, u = (rem >> 4) & 3, d = (rem >> 2) & 3, l = rem & 3;
        if (rr >= 6) continue;
        int p = xl[g * kNSites + rr * 6];
        if (rr == 0) {
            if (u == 0) L[OFF_MS0 + g * 64 + d * 4 + l] = peps[l * 32 + d * 2 + p];
        } else if (rr == 5) {
            if (d == 0) L[OFF_MS5 + g * 64 + u * 4 + l] = peps[5 * 3072 + l * 32 + u * 8 + p];
        } else {
            L[OFF_MS + g * 4096 + (rr - 1) * 1024 + d * 64 + ((u * 4 + l) ^ ((d & 7) << 2))] =
                peps[rr * 3072 + l * 32 + u * 8 + d * 2 + p];
        }
    }
    // prologue: stage A2 for first site (c=1, r=0) into buffer 0
    stage_a2(L, xl, peps, OFF_A2, 1, 0, tid, 512);
    __syncthreads();

    int ab = 0;
    for (int c = 1; c < 6; ++c) {
        for (int r = 0; r < 6; ++r) {
            // ===== PHASE A: generate P half of bond (c-1, r) — all 512 threads =====
            if (r <= 4) {
                const int goff = ((c - 1) * 5 + r) << 11;
                const int j = tid * 2;
                float2 p0 = {0,0}, p1 = {0,0}, p2 = {0,0}, p3 = {0,0};
                const float* wp = W2 + (size_t)goff + j;
#pragma unroll 8
                for (int k = 0; k < 64; ++k) {
                    float2 w  = *reinterpret_cast<const float2*>(wp + (size_t)k * kProj);
                    float4 hv = *reinterpret_cast<float4*>(&L[OFF_HT + (k << 2)]);
                    p0.x = fmaf(w.x, hv.x, p0.x); p0.y = fmaf(w.y, hv.x, p0.y);
                    p1.x = fmaf(w.x, hv.y, p1.x); p1.y = fmaf(w.y, hv.y, p1.y);
                    p2.x = fmaf(w.x, hv.z, p2.x); p2.y = fmaf(w.y, hv.z, p2.y);
                    p3.x = fmaf(w.x, hv.w, p3.x); p3.y = fmaf(w.y, hv.w, p3.y);
                }
                float2 bp = *reinterpret_cast<const float2*>(base_proj + goff + j);
                float2 bb = *reinterpret_cast<const float2*>(b2 + goff + j);
                float2 v;
                v.x = bp.x + kEta*(bb.x + p0.x); v.y = bp.y + kEta*(bb.y + p0.y);
                *reinterpret_cast<float2*>(&L[OFF_M2 + 0*2048 + j]) = v;
                v.x = bp.x + kEta*(bb.x + p1.x); v.y = bp.y + kEta*(bb.y + p1.y);
                *reinterpret_cast<float2*>(&L[OFF_M2 + 1*2048 + j]) = v;
                v.x = bp.x + kEta*(bb.x + p2.x); v.y = bp.y + kEta*(bb.y + p2.y);
                *reinterpret_cast<float2*>(&L[OFF_M2 + 2*2048 + j]) = v;
                v.x = bp.x + kEta*(bb.x + p3.x); v.y = bp.y + kEta*(bb.y + p3.y);
                *reinterpret_cast<float2*>(&L[OFF_M2 + 3*2048 + j]) = v;
                __syncthreads();
            }

            // ===== PHASE B: waves 0-3 contraction (sample = wid); waves 4-7 Q-gen + stage next A2 =====
            if (wid < 4) {
                const int g   = wid;
                const int Pb  = OFF_M2 + g * 2048;   // P aliased at M2h start
                const int M2b = OFF_M2 + g * 2048;
                const int A2b = OFF_A2 + ab * 1024 + g * 256;

                if (r == 0) {
                    // u-dim 1: Mold0[lb][cc] regs, then Ms0_new[cc][rb]
                    const int cc = lane >> 2, rb = lane & 3;
                    float mold0[16];
#pragma unroll
                    for (int i = 0; i < 16; ++i) mold0[i] = 0.0f;
#pragma unroll
                    for (int d = 0; d < 16; ++d) {
                        float4 ms = *reinterpret_cast<float4*>(&L[OFF_MS0 + g*64 + d*4]);
                        float msl[4] = {ms.x, ms.y, ms.z, ms.w};
#pragma unroll
                        for (int b = 0; b < 4; ++b) {
                            float pv = L[Pb + d*64 + b*16 + cc];
#pragma unroll
                            for (int l = 0; l < 4; ++l)
                                mold0[l*4+b] = fmaf(msl[l], pv, mold0[l*4+b]);
                        }
                    }
                    float o = 0.0f;
#pragma unroll
                    for (int lb = 0; lb < 16; ++lb)
                        o = fmaf(mold0[lb], L[A2b + lb*16 + rb], o);
                    L[OFF_MS0 + g*64 + cc*4 + rb] = o;
                } else if (r < 5) {
                    const int u = lane & 15, ccq = lane >> 4;
                    const int msr = OFF_MS + g*4096 + (r-1)*1024;
                    // ---- fused p1: Mold[u][lb][ccq*4..+3] in regs ----
                    float4 mold[16];
#pragma unroll
                    for (int i = 0; i < 16; ++i) mold[i] = make_float4(0,0,0,0);
#pragma unroll
                    for (int d = 0; d < 16; ++d) {
                        const int wsz = (d & 7) << 2;
                        float4 ms = *reinterpret_cast<float4*>(&L[msr + d*64 + ((u*4) ^ wsz)]);
                        float msl[4] = {ms.x, ms.y, ms.z, ms.w};
#pragma unroll
                        for (int b = 0; b < 4; ++b) {
                            float4 p = *reinterpret_cast<float4*>(&L[Pb + d*64 + b*16 + ccq*4]);
#pragma unroll
                            for (int l = 0; l < 4; ++l)
                                mold[l*4+b] = f4fma(msl[l], p, mold[l*4+b]);
                        }
                    }
                    // ---- fused p2: acc[a][cco] (float4 over rb) = M2[(u,a)][(cc,rb)] ----
                    float4 acc[16];
#pragma unroll
                    for (int i = 0; i < 16; ++i) acc[i] = make_float4(0,0,0,0);
#pragma unroll
                    for (int lb = 0; lb < 16; ++lb) {
                        float4 ar0 = *reinterpret_cast<float4*>(&L[A2b + lb*16 + 0]);
                        float4 ar1 = *reinterpret_cast<float4*>(&L[A2b + lb*16 + 4]);
                        float4 ar2 = *reinterpret_cast<float4*>(&L[A2b + lb*16 + 8]);
                        float4 ar3 = *reinterpret_cast<float4*>(&L[A2b + lb*16 + 12]);
                        float mo[4] = {mold[lb].x, mold[lb].y, mold[lb].z, mold[lb].w};
#pragma unroll
                        for (int cco = 0; cco < 4; ++cco) {
                            acc[0*4+cco] = f4fma(mo[cco], ar0, acc[0*4+cco]);
                            acc[1*4+cco] = f4fma(mo[cco], ar1, acc[1*4+cco]);
                            acc[2*4+cco] = f4fma(mo[cco], ar2, acc[2*4+cco]);
                            acc[3*4+cco] = f4fma(mo[cco], ar3, acc[3*4+cco]);
                        }
                    }
                    // ---- 2-pass: write M2 half, p3 (Q @ M2) half ----
                    const int Qb = OFF_Q + ((r-1) & 1) * 4352 + g * 1088;
                    const int cq0 = (lane >> 3) * 2, colg = lane & 7, colh0 = colg * 4;
#pragma unroll
                    for (int ph = 0; ph < 2; ++ph) {
                        if ((ccq >> 1) == ph) {
#pragma unroll
                            for (int a = 0; a < 4; ++a) {
                                const int ua = u*4 + a;
                                const int wsz = (u & 7) << 2;
#pragma unroll
                                for (int cco = 0; cco < 4; ++cco) {
                                    int colh = (ccq & 1) * 16 + cco * 4;
                                    *reinterpret_cast<float4*>(&L[M2b + ua*32 + (colh ^ wsz)]) = acc[a*4+cco];
                                }
                            }
                        }
                        float4 o0 = make_float4(0,0,0,0), o1 = make_float4(0,0,0,0);
#pragma unroll
                        for (int ua0 = 0; ua0 < 64; ua0 += 4) {
                            float4 q0 = *reinterpret_cast<float4*>(&L[Qb + cq0*68 + ua0]);
                            float4 q1 = *reinterpret_cast<float4*>(&L[Qb + (cq0+1)*68 + ua0]);
                            const int wsz = ((ua0 >> 2) & 7) << 2;
                            float4 m0 = *reinterpret_cast<float4*>(&L[M2b + (ua0+0)*32 + (colh0 ^ wsz)]);
                            float4 m1 = *reinterpret_cast<float4*>(&L[M2b + (ua0+1)*32 + (colh0 ^ wsz)]);
                            float4 m2 = *reinterpret_cast<float4*>(&L[M2b + (ua0+2)*32 + (colh0 ^ wsz)]);
                            float4 m3 = *reinterpret_cast<float4*>(&L[M2b + (ua0+3)*32 + (colh0 ^ wsz)]);
                            o0 = f4fma(q0.x, m0, o0); o0 = f4fma(q0.y, m1, o0);
                            o0 = f4fma(q0.z, m2, o0); o0 = f4fma(q0.w, m3, o0);
                            o1 = f4fma(q1.x, m0, o1); o1 = f4fma(q1.y, m1, o1);
                            o1 = f4fma(q1.z, m2, o1); o1 = f4fma(q1.w, m3, o1);
                        }
                        const int dn = ph * 8 + colg;
                        const int wsd = (dn & 7) << 2;
                        *reinterpret_cast<float4*>(&L[msr + dn*64 + ((cq0*4) ^ wsd)]) = o0;
                        *reinterpret_cast<float4*>(&L[msr + dn*64 + (((cq0+1)*4) ^ wsd)]) = o1;
                    }
                } else { // r == 5
                    // p2': M2_5[ua][rb]
                    {
                        const int u5 = lane >> 2, a5 = lane & 3;
                        float4 ms5 = *reinterpret_cast<float4*>(&L[OFF_MS5 + g*64 + u5*4]);
                        float m5l[4] = {ms5.x, ms5.y, ms5.z, ms5.w};
                        float4 o = make_float4(0,0,0,0);
#pragma unroll
                        for (int l = 0; l < 4; ++l) {
                            float4 av = *reinterpret_cast<float4*>(&L[A2b + (l*4)*16 + a5*4]);
                            o = f4fma(m5l[l], av, o);
                        }
                        *reinterpret_cast<float4*>(&L[M2b + lane*4]) = o;
                    }
                    // p3': Ms5_new[cq][rb] = sum_ua Q[cq][ua] * M2_5[ua][rb]
                    {
                        const int cq = lane >> 2, rb = lane & 3;
                        const int Qb = OFF_Q + ((r-1) & 1) * 4352 + g * 1088;
                        float o = 0.0f;
#pragma unroll
                        for (int ua0 = 0; ua0 < 64; ua0 += 4) {
                            float4 q = *reinterpret_cast<float4*>(&L[Qb + cq*68 + ua0]);
                            o = fmaf(q.x, L[M2b + (ua0+0)*4 + rb], o);
                            o = fmaf(q.y, L[M2b + (ua0+1)*4 + rb], o);
                            o = fmaf(q.z, L[M2b + (ua0+2)*4 + rb], o);
                            o = fmaf(q.w, L[M2b + (ua0+3)*4 + rb], o);
                        }
                        L[OFF_MS5 + g*64 + cq*4 + rb] = o;
                    }
                }
            } else {
                // ---- waves 4-7: Q half of bond (c-1, r) (consumed next site) ----
                if (r <= 4) {
                    const int goff = ((c - 1) * 5 + r) << 11;
                    const int j = 1024 + (tid - 256) * 4;
                    float4 q0 = make_float4(0,0,0,0), q1 = q0, q2 = q0, q3 = q0;
                    const float* wp = W2 + (size_t)goff + j;
#pragma unroll 8
                    for (int k = 0; k < 64; ++k) {
                        float4 w  = *reinterpret_cast<const float4*>(wp + (size_t)k * kProj);
                        float4 hv = *reinterpret_cast<float4*>(&L[OFF_HT + (k << 2)]);
                        q0 = f4fma(hv.x, w, q0);
                        q1 = f4fma(hv.y, w, q1);
                        q2 = f4fma(hv.z, w, q2);
                        q3 = f4fma(hv.w, w, q3);
                    }
                    float4 bp = *reinterpret_cast<const float4*>(base_proj + goff + j);
                    float4 bb = *reinterpret_cast<const float4*>(b2 + goff + j);
                    const int qq = j - 1024, cq = qq >> 6, ua0 = qq & 63;
                    const int Qw = OFF_Q + (r & 1) * 4352 + cq * 68 + ua0;
                    float4 v;
                    v.x = bp.x + kEta*(bb.x+q0.x); v.y = bp.y + kEta*(bb.y+q0.y);
                    v.z = bp.z + kEta*(bb.z+q0.z); v.w = bp.w + kEta*(bb.w+q0.w);
                    *reinterpret_cast<float4*>(&L[Qw + 0*1088]) = v;
                    v.x = bp.x + kEta*(bb.x+q1.x); v.y = bp.y + kEta*(bb.y+q1.y);
                    v.z = bp.z + kEta*(bb.z+q1.z); v.w = bp.w + kEta*(bb.w+q1.w);
                    *reinterpret_cast<float4*>(&L[Qw + 1*1088]) = v;
                    v.x = bp.x + kEta*(bb.x+q2.x); v.y = bp.y + kEta*(bb.y+q2.y);
                    v.z = bp.z + kEta*(bb.z+q2.z); v.w = bp.w + kEta*(bb.w+q2.w);
                    *reinterpret_cast<float4*>(&L[Qw + 2*1088]) = v;
                    v.x = bp.x + kEta*(bb.x+q3.x); v.y = bp.y + kEta*(bb.y+q3.y);
                    v.z = bp.z + kEta*(bb.z+q3.z); v.w = bp.w + kEta*(bb.w+q3.w);
                    *reinterpret_cast<float4*>(&L[Qw + 3*1088]) = v;
                }
                // ---- stage next site's A2 ----
                if (!(c == 5 && r == 5)) {
                    int nr = (r < 5) ? r + 1 : 0;
                    int nc = (r < 5) ? c : c + 1;
                    stage_a2(L, xl, peps, OFF_A2 + (ab ^ 1) * 1024, nc, nr, tid - 256, 256);
                }
            }
            __syncthreads();
            ab ^= 1;
        }
    }

    // ---- final chain contraction (per-sample wave, rb = 0 after c=5) ----
    if (wid < 4) {
        const int g = wid;
        if (lane < 16) L[OFF_VB + g*16 + lane] = L[OFF_MS0 + g*64 + lane*4];
        for (int rr = 1; rr < 5; ++rr) {
            float a = 0.0f;
            if (lane < 16) {
#pragma unroll
                for (int u = 0; u < 16; ++u)
                    a = fmaf(L[OFF_VB + g*16 + u],
                             L[OFF_MS + g*4096 + (rr-1)*1024 + lane*64 + ((u*4) ^ ((lane&7)<<2))], a);
            }
            if (lane < 16) L[OFF_VB + g*16 + lane] = a;
        }
        if (lane == 0 && sBase + g < batch) {
            float a = 0.0f;
#pragma unroll
            for (int u = 0; u < 16; ++u)
                a = fmaf(L[OFF_VB + g*16 + u], L[OFF_MS5 + g*64 + u*4], a);
            out[sBase + g] = a;
        }
    }
}

extern "C" void kernel_launch(void* const* d_in, const int* in_sizes, int n_in,
                              void* d_out, int out_size, void* d_ws, size_t ws_size,
                              hipStream_t stream) {
    const int*   x         = (const int*)d_in[0];
    const float* peps      = (const float*)d_in[1];
    const float* base_proj = (const float*)d_in[2];
    const float* W1        = (const float*)d_in[3];
    const float* b1        = (const float*)d_in[4];
    const float* W2        = (const float*)d_in[5];
    const float* b2        = (const float*)d_in[6];
    float*       out       = (float*)d_out;

    const int batch  = in_sizes[0] / kNSites;
    const int blocks = (batch + G - 1) / G;
    hipLaunchKernelGGL(tn_amp, dim3(blocks), dim3(512), 0, stream,
                       x, peps, base_proj, W1, b1, W2, b2, out, batch);
}

// Round 6
// 461.970 us; speedup vs baseline: 1.3328x; 1.3328x over previous
//
#include <hip/hip_runtime.h>

// fTN_NNiso: batched PEPS amplitude, MI355X. TWO-PASS:
//  pass 1 gen_q : q[s][51200] = h_s @ W2 + b2  (bf16 into d_ws; chunked if ws small)
//  pass 2 tn_con: boundary-MPS sweep; P/Q = base_proj + eta*q loaded per site.
// tn_con keeps round-4's validated phase math (one wave per sample, XOR-swizzled
// Ms/M2, 2-pass M2/p3) with p1+p2 restructured b-outer so live accs ~80 floats
// (round-4/5 spilled: mold[16]+acc[16]=128 floats -> 73MB scratch at VGPR=128).
// bf16 q error: eta*0.4%*|q| ~ 1e-5 on vec -> ~8e-9 output absmax (thr 9.6e-8).
// peps strides (6,6,4,4,4,4,2): r:3072 c:512 l:128 rb:32 a:8 b:2 p:1

constexpr int   kNSites = 36;
constexpr int   kProj   = 51200;
constexpr float kEta    = 0.001f;
constexpr int   G       = 4;

__device__ __forceinline__ float4 f4fma(float s, float4 a, float4 c) {
    c.x = fmaf(s, a.x, c.x); c.y = fmaf(s, a.y, c.y);
    c.z = fmaf(s, a.z, c.z); c.w = fmaf(s, a.w, c.w);
    return c;
}
__device__ __forceinline__ unsigned short f2bf(float f) {
    union { float f; unsigned int u; } v; v.f = f;
    unsigned int r = v.u + 0x7FFFu + ((v.u >> 16) & 1u);  // RNE
    return (unsigned short)(r >> 16);
}
__device__ __forceinline__ float bf2f(unsigned int h) {
    union { unsigned int u; float f; } v; v.u = h << 16;
    return v.f;
}

// ===================== PASS 1: q = h @ W2 + b2 (bf16) =====================
__global__ __launch_bounds__(256)
void gen_q(const int* __restrict__ x,
           const float* __restrict__ W1,
           const float* __restrict__ b1,
           const float* __restrict__ W2,
           const float* __restrict__ b2,
           unsigned short* __restrict__ qout,
           int s0, int send)
{
    __shared__ float hT[64 * 64];   // [k*64 + sl]
    __shared__ int   xs[64 * 36];
    const int tid   = threadIdx.x;
    const int sbase = s0 + blockIdx.x * 64;
    const int ns    = blockIdx.y;   // 200 strips of 256 cols

    for (int i = tid; i < 64 * 36; i += 256) {
        int sl = i / 36, ii = i - sl * 36;
        int s = sbase + sl; if (s >= send) s = send - 1;
        xs[i] = x[s * kNSites + ii];
    }
    __syncthreads();
    for (int i = tid; i < 4096; i += 256) {
        int k = i >> 6, sl = i & 63;
        float a = b1[k];
        for (int j = 0; j < kNSites; ++j)
            a = fmaf((float)xs[sl * 36 + j], W1[j * 64 + k], a);
        hT[k * 64 + sl] = fmaxf(a, 0.0f);
    }
    __syncthreads();

    const int sgrp = tid >> 6;            // wave-uniform
    const int c4   = (tid & 63) * 4;
    const int col  = ns * 256 + c4;
    float4 acc[16];
#pragma unroll
    for (int i = 0; i < 16; ++i) acc[i] = make_float4(0, 0, 0, 0);
    const float* wp = W2 + col;
#pragma unroll 4
    for (int k = 0; k < 64; ++k) {
        float4 w = *reinterpret_cast<const float4*>(wp + (size_t)k * kProj);
#pragma unroll
        for (int s4 = 0; s4 < 4; ++s4) {
            float4 hv = *reinterpret_cast<const float4*>(&hT[k * 64 + sgrp * 16 + s4 * 4]);
            acc[s4 * 4 + 0] = f4fma(hv.x, w, acc[s4 * 4 + 0]);
            acc[s4 * 4 + 1] = f4fma(hv.y, w, acc[s4 * 4 + 1]);
            acc[s4 * 4 + 2] = f4fma(hv.z, w, acc[s4 * 4 + 2]);
            acc[s4 * 4 + 3] = f4fma(hv.w, w, acc[s4 * 4 + 3]);
        }
    }
    float4 bb = *reinterpret_cast<const float4*>(b2 + col);
#pragma unroll
    for (int i = 0; i < 16; ++i) {
        int s = sbase + sgrp * 16 + i;
        if (s < send) {
            ushort4 uv;
            uv.x = f2bf(acc[i].x + bb.x); uv.y = f2bf(acc[i].y + bb.y);
            uv.z = f2bf(acc[i].z + bb.z); uv.w = f2bf(acc[i].w + bb.w);
            *reinterpret_cast<ushort4*>(qout + (size_t)(s - s0) * kProj + col) = uv;
        }
    }
}

// ===================== PASS 2: contraction sweep =====================
// LDS layout (float offsets)
constexpr int OFF_MS  = 0;                 // MsT[g][r-1][d][ul ^ ((d&7)<<2)]  4*4096
constexpr int OFF_MS0 = 16384;             // Ms0T[g][d*4+l]                   4*64
constexpr int OFF_MS5 = 16640;             // Ms5[g][u*4+l]                    4*64
constexpr int OFF_Q   = 16896;             // Q[buf][g][cq*68+ua]              2*4*1088
constexpr int OFF_M2  = 16896 + 8704;      // 25600: P alias + M2h per sample 2048
constexpr int OFF_A2  = 25600 + 8192;      // 33792: A2[ab][g][lb*16+a*4+rb]   2*1024
constexpr int OFF_VB  = 33792 + 2048;      // 35840
constexpr int LTOT    = 35904;             // 143,616 B

__device__ __forceinline__ void stage_a2(float* L, const int* xl,
                                         const float* __restrict__ peps,
                                         int dst, int c, int r, int t0, int tstep)
{
    const int adim = (r == 0) ? 1 : 4;
    const int bdim = (r == 5) ? 1 : 4;
    const int rdim = (c == 5) ? 1 : 4;
    for (int idx = t0; idx < G * 256; idx += tstep) {
        int g = idx >> 8, rest = idx & 255;
        int lb = rest >> 4, arb = rest & 15;
        int l = lb >> 2, b = lb & 3, a = arb >> 2, rb = arb & 3;
        float v = 0.0f;
        if (a < adim && b < bdim && rb < rdim) {
            int p = xl[g * kNSites + r * 6 + c];
            v = peps[r * 3072 + c * 512 + l * 128 + rb * 32 + a * 8 + b * 2 + p];
        }
        L[dst + idx] = v;
    }
}

__global__ __launch_bounds__(512)
void tn_con(const int* __restrict__ x,
            const float* __restrict__ peps,
            const float* __restrict__ base_proj,
            const unsigned short* __restrict__ qc,
            float* __restrict__ out,
            int s0, int send)
{
    __shared__ __align__(16) float L[LTOT];
    __shared__ int xl[G * kNSites];

    const int tid   = threadIdx.x;
    const int wid   = tid >> 6;
    const int lane  = tid & 63;
    const int sBase = s0 + blockIdx.x * G;

    // per-thread sample (for P-load: g = tid>>7; for Q-stage: g = (tid-256)>>6)
    const int gP = tid >> 7;
    int sP = sBase + gP; if (sP >= send) sP = send - 1;
    const size_t qbP = (size_t)(sP - s0) * kProj;
    const int gQ = (tid - 256) >> 6;
    int sQ = sBase + ((gQ >= 0 && gQ < 4) ? gQ : 0); if (sQ >= send) sQ = send - 1;
    const size_t qbQ = (size_t)(sQ - s0) * kProj;

    if (tid < G * kNSites) {
        int g = tid / kNSites, ii = tid - g * kNSites;
        int s = sBase + g; if (s >= send) s = send - 1;
        xl[tid] = x[s * kNSites + ii];
    }
    for (int i = tid; i < 16896; i += 512) L[OFF_MS + i] = 0.0f;
    __syncthreads();

    // init boundary MPS from column 0
    for (int idx = tid; idx < 2048; idx += 512) {
        int g = idx >> 9, rem = idx & 511;
        int rr = rem >> 6, u = (rem >> 4) & 3, d = (rem >> 2) & 3, l = rem & 3;
        if (rr >= 6) continue;
        int p = xl[g * kNSites + rr * 6];
        if (rr == 0) {
            if (u == 0) L[OFF_MS0 + g * 64 + d * 4 + l] = peps[l * 32 + d * 2 + p];
        } else if (rr == 5) {
            if (d == 0) L[OFF_MS5 + g * 64 + u * 4 + l] = peps[5 * 3072 + l * 32 + u * 8 + p];
        } else {
            L[OFF_MS + g * 4096 + (rr - 1) * 1024 + d * 64 + ((u * 4 + l) ^ ((d & 7) << 2))] =
                peps[rr * 3072 + l * 32 + u * 8 + d * 2 + p];
        }
    }
    stage_a2(L, xl, peps, OFF_A2, 1, 0, tid, 512);
    __syncthreads();

    int ab = 0;
    for (int c = 1; c < 6; ++c) {
        for (int r = 0; r < 6; ++r) {
            // ---- load P (bond c-1,r first half) into M2-alias region ----
            if (r <= 4) {
                const int goff = ((c - 1) * 5 + r) << 11;
                const int j = (tid & 127) * 8;
                const float* bp = base_proj + goff + j;
                float4 b0 = *reinterpret_cast<const float4*>(bp);
                float4 b1v = *reinterpret_cast<const float4*>(bp + 4);
                uint4 qv = *reinterpret_cast<const uint4*>(qc + qbP + goff + j);
                float4 o0, o1;
                o0.x = b0.x + kEta * bf2f(qv.x & 0xffffu);
                o0.y = b0.y + kEta * bf2f(qv.x >> 16);
                o0.z = b0.z + kEta * bf2f(qv.y & 0xffffu);
                o0.w = b0.w + kEta * bf2f(qv.y >> 16);
                o1.x = b1v.x + kEta * bf2f(qv.z & 0xffffu);
                o1.y = b1v.y + kEta * bf2f(qv.z >> 16);
                o1.z = b1v.z + kEta * bf2f(qv.w & 0xffffu);
                o1.w = b1v.w + kEta * bf2f(qv.w >> 16);
                *reinterpret_cast<float4*>(&L[OFF_M2 + gP * 2048 + j]) = o0;
                *reinterpret_cast<float4*>(&L[OFF_M2 + gP * 2048 + j + 4]) = o1;
                __syncthreads();
            }

            if (wid < 4) {
                const int g   = wid;
                const int Pb  = OFF_M2 + g * 2048;
                const int M2b = OFF_M2 + g * 2048;
                const int A2b = OFF_A2 + ab * 1024 + g * 256;

                if (r == 0) {
                    const int cc = lane >> 2, rb = lane & 3;
                    float mold0[16];
#pragma unroll
                    for (int i = 0; i < 16; ++i) mold0[i] = 0.0f;
#pragma unroll
                    for (int d = 0; d < 16; ++d) {
                        float4 ms = *reinterpret_cast<float4*>(&L[OFF_MS0 + g*64 + d*4]);
                        float msl[4] = {ms.x, ms.y, ms.z, ms.w};
#pragma unroll
                        for (int b = 0; b < 4; ++b) {
                            float pv = L[Pb + d*64 + b*16 + cc];
#pragma unroll
                            for (int l = 0; l < 4; ++l)
                                mold0[l*4+b] = fmaf(msl[l], pv, mold0[l*4+b]);
                        }
                    }
                    float o = 0.0f;
#pragma unroll
                    for (int lb = 0; lb < 16; ++lb)
                        o = fmaf(mold0[lb], L[A2b + lb*16 + rb], o);
                    L[OFF_MS0 + g*64 + cc*4 + rb] = o;
                } else if (r < 5) {
                    const int u = lane & 15, ccq = lane >> 4;
                    const int msr = OFF_MS + g*4096 + (r-1)*1024;
                    // ---- b-outer fused p1+p2: acc[16] + mold[4] live ----
                    float4 acc[16];
#pragma unroll
                    for (int i = 0; i < 16; ++i) acc[i] = make_float4(0,0,0,0);
#pragma unroll
                    for (int b = 0; b < 4; ++b) {
                        asm volatile("" ::: "memory");   // keep Ms/P reads per-b (reg pressure)
                        float4 mold[4] = {make_float4(0,0,0,0), make_float4(0,0,0,0),
                                          make_float4(0,0,0,0), make_float4(0,0,0,0)};
#pragma unroll
                        for (int d = 0; d < 16; ++d) {
                            const int wsz = (d & 7) << 2;
                            float4 ms = *reinterpret_cast<float4*>(&L[msr + d*64 + ((u*4) ^ wsz)]);
                            float4 p  = *reinterpret_cast<float4*>(&L[Pb + d*64 + b*16 + ccq*4]);
                            mold[0] = f4fma(ms.x, p, mold[0]);
                            mold[1] = f4fma(ms.y, p, mold[1]);
                            mold[2] = f4fma(ms.z, p, mold[2]);
                            mold[3] = f4fma(ms.w, p, mold[3]);
                        }
#pragma unroll
                        for (int l = 0; l < 4; ++l) {
                            float ml[4] = {mold[l].x, mold[l].y, mold[l].z, mold[l].w};
#pragma unroll
                            for (int a = 0; a < 4; ++a) {
                                float4 av = *reinterpret_cast<float4*>(&L[A2b + (l*4+b)*16 + a*4]);
#pragma unroll
                                for (int cco = 0; cco < 4; ++cco)
                                    acc[a*4+cco] = f4fma(ml[cco], av, acc[a*4+cco]);
                            }
                        }
                    }
                    // ---- 2-pass: write M2 half, p3 (Q @ M2) half ----
                    const int Qb = OFF_Q + ((r-1) & 1) * 4352 + g * 1088;
                    const int cq0 = (lane >> 3) * 2, colg = lane & 7, colh0 = colg * 4;
#pragma unroll
                    for (int ph = 0; ph < 2; ++ph) {
                        if ((ccq >> 1) == ph) {
#pragma unroll
                            for (int a = 0; a < 4; ++a) {
                                const int ua = u*4 + a;
                                const int wsz = (u & 7) << 2;
#pragma unroll
                                for (int cco = 0; cco < 4; ++cco) {
                                    int colh = (ccq & 1) * 16 + cco * 4;
                                    *reinterpret_cast<float4*>(&L[M2b + ua*32 + (colh ^ wsz)]) = acc[a*4+cco];
                                }
                            }
                        }
                        float4 o0 = make_float4(0,0,0,0), o1 = make_float4(0,0,0,0);
#pragma unroll
                        for (int ua0 = 0; ua0 < 64; ua0 += 4) {
                            float4 q0 = *reinterpret_cast<float4*>(&L[Qb + cq0*68 + ua0]);
                            float4 q1 = *reinterpret_cast<float4*>(&L[Qb + (cq0+1)*68 + ua0]);
                            const int wsz = ((ua0 >> 2) & 7) << 2;
                            float4 m0 = *reinterpret_cast<float4*>(&L[M2b + (ua0+0)*32 + (colh0 ^ wsz)]);
                            float4 m1 = *reinterpret_cast<float4*>(&L[M2b + (ua0+1)*32 + (colh0 ^ wsz)]);
                            float4 m2 = *reinterpret_cast<float4*>(&L[M2b + (ua0+2)*32 + (colh0 ^ wsz)]);
                            float4 m3 = *reinterpret_cast<float4*>(&L[M2b + (ua0+3)*32 + (colh0 ^ wsz)]);
                            o0 = f4fma(q0.x, m0, o0); o0 = f4fma(q0.y, m1, o0);
                            o0 = f4fma(q0.z, m2, o0); o0 = f4fma(q0.w, m3, o0);
                            o1 = f4fma(q1.x, m0, o1); o1 = f4fma(q1.y, m1, o1);
                            o1 = f4fma(q1.z, m2, o1); o1 = f4fma(q1.w, m3, o1);
                        }
                        const int dn = ph * 8 + colg;
                        const int wsd = (dn & 7) << 2;
                        *reinterpret_cast<float4*>(&L[msr + dn*64 + ((cq0*4) ^ wsd)]) = o0;
                        *reinterpret_cast<float4*>(&L[msr + dn*64 + (((cq0+1)*4) ^ wsd)]) = o1;
                    }
                } else { // r == 5
                    {
                        const int u5 = lane >> 2, a5 = lane & 3;
                        float4 ms5 = *reinterpret_cast<float4*>(&L[OFF_MS5 + g*64 + u5*4]);
                        float m5l[4] = {ms5.x, ms5.y, ms5.z, ms5.w};
                        float4 o = make_float4(0,0,0,0);
#pragma unroll
                        for (int l = 0; l < 4; ++l) {
                            float4 av = *reinterpret_cast<float4*>(&L[A2b + (l*4)*16 + a5*4]);
                            o = f4fma(m5l[l], av, o);
                        }
                        *reinterpret_cast<float4*>(&L[M2b + lane*4]) = o;
                    }
                    {
                        const int cq = lane >> 2, rb = lane & 3;
                        const int Qb = OFF_Q + ((r-1) & 1) * 4352 + g * 1088;
                        float o = 0.0f;
#pragma unroll
                        for (int ua0 = 0; ua0 < 64; ua0 += 4) {
                            float4 q = *reinterpret_cast<float4*>(&L[Qb + cq*68 + ua0]);
                            o = fmaf(q.x, L[M2b + (ua0+0)*4 + rb], o);
                            o = fmaf(q.y, L[M2b + (ua0+1)*4 + rb], o);
                            o = fmaf(q.z, L[M2b + (ua0+2)*4 + rb], o);
                            o = fmaf(q.w, L[M2b + (ua0+3)*4 + rb], o);
                        }
                        L[OFF_MS5 + g*64 + cq*4 + rb] = o;
                    }
                }
            } else {
                // ---- waves 4-7: stage Q(c-1, r) from global vec; stage next A2 ----
                const int t = tid - 256;
                if (r <= 4) {
                    const int goff2 = (((c - 1) * 5 + r) << 11) + 1024;
                    const int j0 = (t & 63) * 4;
                    const int qdst = OFF_Q + (r & 1) * 4352 + gQ * 1088;
#pragma unroll
                    for (int ch = 0; ch < 4; ++ch) {
                        int jj = j0 + ch * 256;
                        float4 bb = *reinterpret_cast<const float4*>(base_proj + goff2 + jj);
                        uint2 qv = *reinterpret_cast<const uint2*>(qc + qbQ + goff2 + jj);
                        float4 v;
                        v.x = bb.x + kEta * bf2f(qv.x & 0xffffu);
                        v.y = bb.y + kEta * bf2f(qv.x >> 16);
                        v.z = bb.z + kEta * bf2f(qv.y & 0xffffu);
                        v.w = bb.w + kEta * bf2f(qv.y >> 16);
                        *reinterpret_cast<float4*>(&L[qdst + (jj >> 6) * 68 + (jj & 63)]) = v;
                    }
                }
                if (!(c == 5 && r == 5)) {
                    int nr = (r < 5) ? r + 1 : 0;
                    int nc = (r < 5) ? c : c + 1;
                    stage_a2(L, xl, peps, OFF_A2 + (ab ^ 1) * 1024, nc, nr, t, 256);
                }
            }
            __syncthreads();
            ab ^= 1;
        }
    }

    // ---- final chain contraction ----
    if (wid < 4) {
        const int g = wid;
        if (lane < 16) L[OFF_VB + g*16 + lane] = L[OFF_MS0 + g*64 + lane*4];
        for (int rr = 1; rr < 5; ++rr) {
            float a = 0.0f;
            if (lane < 16) {
#pragma unroll
                for (int u = 0; u < 16; ++u)
                    a = fmaf(L[OFF_VB + g*16 + u],
                             L[OFF_MS + g*4096 + (rr-1)*1024 + lane*64 + ((u*4) ^ ((lane&7)<<2))], a);
            }
            if (lane < 16) L[OFF_VB + g*16 + lane] = a;
        }
        if (lane == 0 && sBase + g < send) {
            float a = 0.0f;
#pragma unroll
            for (int u = 0; u < 16; ++u)
                a = fmaf(L[OFF_VB + g*16 + u], L[OFF_MS5 + g*64 + u*4], a);
            out[sBase + g] = a;
        }
    }
}

extern "C" void kernel_launch(void* const* d_in, const int* in_sizes, int n_in,
                              void* d_out, int out_size, void* d_ws, size_t ws_size,
                              hipStream_t stream) {
    const int*   x         = (const int*)d_in[0];
    const float* peps      = (const float*)d_in[1];
    const float* base_proj = (const float*)d_in[2];
    const float* W1        = (const float*)d_in[3];
    const float* b1        = (const float*)d_in[4];
    const float* W2        = (const float*)d_in[5];
    const float* b2        = (const float*)d_in[6];
    float*       out       = (float*)d_out;

    const int batch = in_sizes[0] / kNSites;
    const size_t perS = (size_t)kProj * 2;  // bf16 bytes per sample
    int cs = (int)(ws_size / perS);
    if (cs > batch) cs = batch;
    cs &= ~3;
    if (cs < 4) cs = 4;  // requires ws_size >= 409600 B

    for (int s0 = 0; s0 < batch; s0 += cs) {
        int send = s0 + cs; if (send > batch) send = batch;
        int n = send - s0;
        dim3 g1((n + 63) / 64, 200);
        hipLaunchKernelGGL(gen_q, g1, dim3(256), 0, stream,
                           x, W1, b1, W2, b2, (unsigned short*)d_ws, s0, send);
        hipLaunchKernelGGL(tn_con, dim3((n + 3) / 4), dim3(512), 0, stream,
                           x, peps, base_proj, (const unsigned short*)d_ws, out, s0, send);
    }
}